// Round 12
// baseline (13.564 us; speedup 1.0000x reference)
//
#include <hip/hip_runtime.h>
#include <math.h>

// 8-qubit statevector sim, TWO elements per 64-lane wave (32 lanes each).
// Merge of two VALIDATED kernels: R7's L=32 bit-maps + R9's mechanics
// (LDS scalar table, gate folds into trees, batch amps).
// Storage z: z0-4 = lane sl (5 bits), z5-7 = reg κ (κ0=z5,κ1=z6,κ2=z7), 8 amps.
// Gates: q0:κ2(fold A) q1:κ1(explicit) q2:κ0(fold B) q3:xor16(sel sl4)
//        q4:xor8(sl3) q5:xor7(sl2) q6:xor2(sl1^sl2) q7:xor1(sl0^sl2)
// Product comps: q0:b01^κ2 q1:b01^κ1^κ2 q2:κ0^κ1 q3:sl4^κ0 q4:sl3^sl4
//        q5:sl2^sl3 q6:sl1 q7:sl0^sl1     (b01 = sl0^sl2)
// Phases: E0(±κ2),E1(±κ1) in A; E2(±κ0) in B; lam = ±h3(sl4) ±h4(sl3)
//        ±h5(sl2) ±h6(sl1^sl2) ±h7(sl0^sl2)
// Z Walsh (R7-validated): k-masks q0:0x3 q1:0x6 q2..7:0x7; lane picks
//        q0:31 q1:0 q2:0 q3:16 q4:24 q5:28 q6:26 q7:31.

#define DEVINL __device__ __forceinline__

DEVINL void fast_sincos_half(float x, float& s, float& c) {
    const float r = x * 0.07957747154594767f;   // (x/2)/(2*pi): HW trig in revolutions
    s = __builtin_amdgcn_sinf(r);
    c = __builtin_amdgcn_cosf(r);
}

DEVINL float fast_tanh(float x) {
    const float t = __builtin_amdgcn_exp2f(x * 2.8853900817779268f);  // e^{2x}
    return 1.0f - 2.0f * __builtin_amdgcn_rcpf(t + 1.0f);
}

DEVINL void cmul(float ar, float ai, float br, float bi, float& cr, float& ci) {
    cr = ar*br - ai*bi;  ci = ar*bi + ai*br;
}
DEVINL void cmulc(float ar, float ai, float br, float bi, float& cr, float& ci) {
    cr = ar*br + ai*bi;  ci = ar*bi - ai*br;   // conj(a)*b
}

template<int CTRL>
DEVINL float dpp_perm(float x) {
    return __int_as_float(__builtin_amdgcn_update_dpp(
        __float_as_int(x), __float_as_int(x), CTRL, 0xF, 0xF, false));
}
// DPP: xor1=0xB1 (quad 1,0,3,2); xor2=0x4E (2,3,0,1);
//      xor7=0x141 (row_half_mirror); xor8=0x128 (row_ror:8).
template<int OFF>
DEVINL float swz(float x) {
    return __int_as_float(__builtin_amdgcn_ds_swizzle(__float_as_int(x), OFF));
}
// BitMode: src = ((l&and)|or)^xor within 32-lane halves.
//   xor16 = 0x401F; xor4 = 0x101F; bcast lane31 = 0x3E0; bcast lane0 = 0x000.

// v = Rot(phi,theta,omega) * RX(x) * |0>   (layer-1, validated rounds 3-11)
DEVINL void qubit_vec(float x, float phi, float theta, float omega,
                      float& v0r, float& v0i, float& v1r, float& v1i)
{
    float s, c;   fast_sincos_half(x, s, c);
    float st, ct; fast_sincos_half(theta, st, ct);
    float sa, ca; fast_sincos_half(phi + omega, sa, ca);
    float sb, cb; fast_sincos_half(phi - omega, sb, cb);
    const float A = c*ct, B = s*st, C = c*st, D = s*ct;
    v0r = ca*A - sb*B;  v0i = cb*B - sa*A;
    v1r = cb*C + sa*D;  v1i = -(sb*C + ca*D);
}

__global__ __launch_bounds__(256, 6)
void qcirc_kernel(const float* __restrict__ inputs,
                  const float* __restrict__ hidden,
                  float* __restrict__ out, int B)
{
    __shared__ __align__(16) float lds[512];   // 8 elem x 8 qubits x 8 floats

    const int t  = threadIdx.x;
    const int e  = blockIdx.x * 8 + (t >> 5);
    if (e >= B) return;
    const int sl = t & 31;
    const int gb = t & 32;                 // wave-half base (for the one shfl)
    const int q  = sl & 7;                 // owned qubit (4x replicated owners)
    const int eb = (t >> 5) * 64;          // element base in LDS (floats)
    const int sl0 = sl & 1, sl1 = (sl >> 1) & 1, sl2 = (sl >> 2) & 1,
              sl3 = (sl >> 3) & 1, sl4 = (sl >> 4) & 1;

    // ---- owner compute; lanes sl<8 write the per-element LDS table ----
    const float  x  = inputs[(size_t)e * 8 + q];
    const float* hb = hidden + (size_t)e * 48 + q * 3;
    const float ph1 = hb[0], th1 = hb[1], om1 = hb[2];
    const float ph2 = hb[24], th2 = hb[25];        // layer-2 omega cancels

    float ov0r, ov0i, ov1r, ov1i;
    qubit_vec(x, ph1, th1, om1, ov0r, ov0i, ov1r, ov1i);
    float s2o, c2o; fast_sincos_half(th2, s2o, c2o);
    const float ho = ph2 * 0.07957747154594767f;   // phi2/2 in revolutions
    const float Ec = __builtin_amdgcn_cosf(ho);
    const float Es = __builtin_amdgcn_sinf(ho);
    const float Av = (q < 3) ? Ec : ho;            // q<3: E=(cos,sin); else raw h
    const float Bv = (q < 3) ? Es : 0.f;

    if (sl < 8) {
        *(float4*)(lds + eb + q*8)     = make_float4(ov0r, ov0i, ov1r, ov1i);
        *(float4*)(lds + eb + q*8 + 4) = make_float4(c2o, s2o, Av, Bv);
    }
    // producer and consumers are the SAME wave: lgkmcnt ordering suffices.

    // ---- lane product L over q4..q7 ----
    float Lr, Li;
    {
        const float4 r4 = *(const float4*)(lds + eb + 32);
        const float4 r5 = *(const float4*)(lds + eb + 40);
        const float4 r6 = *(const float4*)(lds + eb + 48);
        const float4 r7 = *(const float4*)(lds + eb + 56);
        const int s4 = sl3 ^ sl4, s5 = sl2 ^ sl3, s6 = sl1, s7 = sl0 ^ sl1;
        const float a4r = s4 ? r4.z : r4.x, a4i = s4 ? r4.w : r4.y;
        const float a5r = s5 ? r5.z : r5.x, a5i = s5 ? r5.w : r5.y;
        const float a6r = s6 ? r6.z : r6.x, a6i = s6 ? r6.w : r6.y;
        const float a7r = s7 ? r7.z : r7.x, a7i = s7 ? r7.w : r7.y;
        float tr, ti;
        cmul(a4r, a4i, a5r, a5i, tr, ti);
        cmul(tr, ti, a6r, a6i, Lr, Li);
        cmul(Lr, Li, a7r, a7i, tr, ti); Lr = tr; Li = ti;
    }
    // ---- lam phase on L (raw h of q3..q7) ----
    {
        const float h3 = lds[eb + 3*8 + 6];
        const float h4 = lds[eb + 4*8 + 6];
        const float h5 = lds[eb + 5*8 + 6];
        const float h6 = lds[eb + 6*8 + 6];
        const float h7 = lds[eb + 7*8 + 6];
        const float lam = (sl4 ? h3 : -h3) + (sl3 ? h4 : -h4) + (sl2 ? h5 : -h5)
                        + ((sl1 ^ sl2) ? h6 : -h6) + ((sl0 ^ sl2) ? h7 : -h7);
        const float Pc = __builtin_amdgcn_cosf(lam);
        const float Ps = __builtin_amdgcn_sinf(lam);
        float tr, ti; cmul(Lr, Li, Pc, Ps, tr, ti); Lr = tr; Li = ti;
    }

    // ---- A[(κ2,κ1)] = w0[κ2]*w1[κ1^κ2]*E0^{±κ2}E1^{±κ1}, q0 folded ----
    float Ar[4], Ai[4];
    {
        const float4 r0 = *(const float4*)(lds + eb + 0);
        const float4 r1 = *(const float4*)(lds + eb + 8);
        const float2 E0 = *(const float2*)(lds + eb + 0*8 + 6);
        const float2 E1 = *(const float2*)(lds + eb + 1*8 + 6);
        const int b01 = sl0 ^ sl2;
        const float w00r = b01 ? r0.z : r0.x, w00i = b01 ? r0.w : r0.y;
        const float w01r = b01 ? r0.x : r0.z, w01i = b01 ? r0.y : r0.w;
        const float w10r = b01 ? r1.z : r1.x, w10i = b01 ? r1.w : r1.y;
        const float w11r = b01 ? r1.x : r1.z, w11i = b01 ? r1.y : r1.w;
        const float aa = E0.x*E1.x, bb = E0.y*E1.y, cc = E0.x*E1.y, dd = E0.y*E1.x;
        const float P3r = aa - bb, P3i = cc + dd;   // E0*E1
        const float P1r = aa + bb, P1i = cc - dd;   // conj(E0)*E1
        float tr, ti;
        cmul(w00r,w00i, w10r,w10i, tr,ti); cmulc(P3r,P3i, tr,ti, Ar[0],Ai[0]);
        cmul(w00r,w00i, w11r,w11i, tr,ti); cmul (P1r,P1i, tr,ti, Ar[1],Ai[1]);
        cmul(w01r,w01i, w11r,w11i, tr,ti); cmulc(P1r,P1i, tr,ti, Ar[2],Ai[2]);
        cmul(w01r,w01i, w10r,w10i, tr,ti); cmul (P3r,P3i, tr,ti, Ar[3],Ai[3]);
        const float2 cs0 = *(const float2*)(lds + eb + 0*8 + 4);   // q0 fold (κ2)
        #pragma unroll
        for (int j = 0; j < 2; ++j) {
            const float lr = Ar[j], li = Ai[j], hr = Ar[j+2], hi = Ai[j+2];
            Ar[j]   = cs0.x*lr - cs0.y*hr;  Ai[j]   = cs0.x*li - cs0.y*hi;
            Ar[j+2] = cs0.y*lr + cs0.x*hr;  Ai[j+2] = cs0.y*li + cs0.x*hi;
        }
    }

    // ---- B[(κ1,κ0)] = v2[κ0^κ1] * (w3[κ0]*E2^{±κ0}), q2 folded (κ0) ----
    float Br[4], Bi[4];
    {
        const float4 r2 = *(const float4*)(lds + eb + 16);
        const float4 r3 = *(const float4*)(lds + eb + 24);
        const float2 E2 = *(const float2*)(lds + eb + 2*8 + 6);
        const float w30r = sl4 ? r3.z : r3.x, w30i = sl4 ? r3.w : r3.y;
        const float w31r = sl4 ? r3.x : r3.z, w31i = sl4 ? r3.y : r3.w;
        float w3p0r, w3p0i, w3p1r, w3p1i;
        cmulc(E2.x, E2.y, w30r, w30i, w3p0r, w3p0i);   // w3[0]*conj(E2)
        cmul (w31r, w31i, E2.x, E2.y, w3p1r, w3p1i);   // w3[1]*E2
        cmul(r2.x, r2.y, w3p0r, w3p0i, Br[0], Bi[0]);
        cmul(r2.z, r2.w, w3p1r, w3p1i, Br[1], Bi[1]);
        cmul(r2.z, r2.w, w3p0r, w3p0i, Br[2], Bi[2]);
        cmul(r2.x, r2.y, w3p1r, w3p1i, Br[3], Bi[3]);
        const float2 cs2 = *(const float2*)(lds + eb + 2*8 + 4);   // q2 fold (κ0)
        #pragma unroll
        for (int j = 0; j < 4; j += 2) {
            const float lr = Br[j], li = Bi[j], hr = Br[j+1], hi = Bi[j+1];
            Br[j]   = cs2.x*lr - cs2.y*hr;  Bi[j]   = cs2.x*li - cs2.y*hi;
            Br[j+1] = cs2.y*lr + cs2.x*hr;  Bi[j+1] = cs2.y*li + cs2.x*hi;
        }
    }

    // ---- init 8 amps: a[k] = A[k>>1] * B[k&3] * L ----
    float ar[8], ai[8];
    #pragma unroll
    for (int k = 0; k < 8; ++k) {
        float tr, ti;
        cmul(Ar[k >> 1], Ai[k >> 1], Br[k & 3], Bi[k & 3], tr, ti);
        cmul(tr, ti, Lr, Li, ar[k], ai[k]);
    }

    // ---- q1 gate (mask κ1 = reg bit1, straddles trees) ----
    {
        const float2 cs = *(const float2*)(lds + eb + 1*8 + 4);
        #pragma unroll
        for (int k = 0; k < 8; ++k) {
            if (k & 2) continue;
            const int k1 = k | 2;
            const float lr = ar[k], li = ai[k], hr = ar[k1], hi = ai[k1];
            ar[k]  = cs.x*lr - cs.y*hr;  ai[k]  = cs.x*li - cs.y*hi;
            ar[k1] = cs.y*lr + cs.x*hr;  ai[k1] = cs.y*li + cs.x*hi;
        }
    }

    // ---- lane gates q3..q7 (swizzle/DPP, VALU-heavy, 8-wide ILP) ----
    {   // q3: xor16 (ds_swizzle), sel sl4
        const float2 cs = *(const float2*)(lds + eb + 3*8 + 4);
        const float se = sl4 ? cs.y : -cs.y;
        #pragma unroll
        for (int k = 0; k < 8; ++k) {
            ar[k] = cs.x*ar[k] + se*swz<0x401F>(ar[k]);
            ai[k] = cs.x*ai[k] + se*swz<0x401F>(ai[k]);
        }
    }
    {   // q4: xor8 (row_ror:8), sel sl3
        const float2 cs = *(const float2*)(lds + eb + 4*8 + 4);
        const float se = sl3 ? cs.y : -cs.y;
        #pragma unroll
        for (int k = 0; k < 8; ++k) {
            ar[k] = cs.x*ar[k] + se*dpp_perm<0x128>(ar[k]);
            ai[k] = cs.x*ai[k] + se*dpp_perm<0x128>(ai[k]);
        }
    }
    {   // q5: xor7 (row_half_mirror), sel sl2
        const float2 cs = *(const float2*)(lds + eb + 5*8 + 4);
        const float se = sl2 ? cs.y : -cs.y;
        #pragma unroll
        for (int k = 0; k < 8; ++k) {
            ar[k] = cs.x*ar[k] + se*dpp_perm<0x141>(ar[k]);
            ai[k] = cs.x*ai[k] + se*dpp_perm<0x141>(ai[k]);
        }
    }
    {   // q6: xor2 (quad), sel sl1^sl2
        const float2 cs = *(const float2*)(lds + eb + 6*8 + 4);
        const float se = (sl1 ^ sl2) ? cs.y : -cs.y;
        #pragma unroll
        for (int k = 0; k < 8; ++k) {
            ar[k] = cs.x*ar[k] + se*dpp_perm<0x4E>(ar[k]);
            ai[k] = cs.x*ai[k] + se*dpp_perm<0x4E>(ai[k]);
        }
    }
    {   // q7: xor1 (quad), sel sl0^sl2
        const float2 cs = *(const float2*)(lds + eb + 7*8 + 4);
        const float se = (sl0 ^ sl2) ? cs.y : -cs.y;
        #pragma unroll
        for (int k = 0; k < 8; ++k) {
            ar[k] = cs.x*ar[k] + se*dpp_perm<0xB1>(ar[k]);
            ai[k] = cs.x*ai[k] + se*dpp_perm<0xB1>(ai[k]);
        }
    }

    // ---- Z expectations: k-part Walsh (masks 0x3, 0x6, 0x7) ----
    float P[8];
    #pragma unroll
    for (int k = 0; k < 8; ++k) P[k] = ar[k]*ar[k] + ai[k]*ai[k];
    const float u0 = P[0]+P[1], v0 = P[0]-P[1];
    const float u1 = P[2]+P[3], v1 = P[2]-P[3];
    const float u2 = P[4]+P[5], v2 = P[4]-P[5];
    const float u3 = P[6]+P[7], v3 = P[6]-P[7];
    float V3 = v0 - v1 + v2 - v3;    // (-1)^{κ1+κ0}
    float V6 = u0 - u1 - u2 + u3;    // (-1)^{κ2+κ1}
    float V7 = v0 - v1 - v2 + v3;    // (-1)^{κ2+κ1+κ0}

    // ---- FWHT over 5 lane bits (xor1,2,8 DPP; xor4,16 swizzle) ----
    {
        const float g1 = (sl & 1) ? -1.f : 1.f;
        V3 = fmaf(g1, V3, dpp_perm<0xB1>(V3));
        V6 = fmaf(g1, V6, dpp_perm<0xB1>(V6));
        V7 = fmaf(g1, V7, dpp_perm<0xB1>(V7));
        const float g2 = (sl & 2) ? -1.f : 1.f;
        V3 = fmaf(g2, V3, dpp_perm<0x4E>(V3));
        V6 = fmaf(g2, V6, dpp_perm<0x4E>(V6));
        V7 = fmaf(g2, V7, dpp_perm<0x4E>(V7));
        const float g4 = (sl & 4) ? -1.f : 1.f;
        V3 = fmaf(g4, V3, swz<0x101F>(V3));
        V6 = fmaf(g4, V6, swz<0x101F>(V6));
        V7 = fmaf(g4, V7, swz<0x101F>(V7));
        const float g8 = (sl & 8) ? -1.f : 1.f;
        V3 = fmaf(g8, V3, dpp_perm<0x128>(V3));
        V6 = fmaf(g8, V6, dpp_perm<0x128>(V6));
        V7 = fmaf(g8, V7, dpp_perm<0x128>(V7));
        const float g16 = (sl & 16) ? -1.f : 1.f;
        V3 = fmaf(g16, V3, swz<0x401F>(V3));
        V6 = fmaf(g16, V6, swz<0x401F>(V6));
        V7 = fmaf(g16, V7, swz<0x401F>(V7));
    }

    // ---- gather per-qubit results, tanh, store (R7-validated picks) ----
    // q0: V3@31  q1: V6@0  q2: V7@0  q3: V7@16  q4: V7@24  q5: V7@28
    // q6: V7@26  q7: V7@31
    const int idx7 = (sl == 3) ? 16 : (sl == 4) ? 24 : (sl == 5) ? 28
                   : (sl == 6) ? 26 : (sl == 7) ? 31 : 0;
    const float B3 = swz<0x3E0>(V3);                 // bcast lane31 of half
    const float B6 = swz<0x000>(V6);                 // bcast lane0 of half
    const float B7 = __shfl(V7, gb + idx7, 64);
    const float rsel = (sl == 0) ? B3 : (sl == 1) ? B6 : B7;
    const float h = fast_tanh(rsel);
    if (sl < 8) {
        const size_t obase = (size_t)e * 8;
        out[obase + sl] = h;
        out[(size_t)B * 8 + obase + sl] = h;
    }
}

extern "C" void kernel_launch(void* const* d_in, const int* in_sizes, int n_in,
                              void* d_out, int out_size, void* d_ws, size_t ws_size,
                              hipStream_t stream)
{
    const float* inputs = (const float*)d_in[0];   // (B, 8) fp32
    const float* hidden = (const float*)d_in[1];   // (B, 2, 1, 8, 3) fp32
    float* out = (float*)d_out;                    // (2, B, 8) fp32 (tuple (h,h))
    const int B = in_sizes[0] / 8;                 // 16384
    const int blocks = (B + 7) / 8;                // 32 lanes per element
    hipLaunchKernelGGL(qcirc_kernel, dim3(blocks), dim3(256), 0, stream,
                       inputs, hidden, out, B);
}